// Round 10
// baseline (669.821 us; speedup 1.0000x reference)
//
#include <hip/hip_runtime.h>
#include <hip/hip_fp16.h>

// GCN 2-layer. Partition (391 x 256-node dst buckets) -> srcnorm -> transform1
// -> agg1 (per-bucket LDS fp32 aggregation via ds_add_f32, 1024-thr blocks,
//    fused norms/relu/W2) -> agg2 (same, fused bias). No CSR pass at all.

#define NB   391      // buckets = ceil(100000/256); bucket = id >> 8
#define CAPB 5504     // padded per-bucket edge capacity (avg 4092, +22 sigma)
#define EPB  4096     // edges per partition block (16/thread)

__device__ __forceinline__ long nt_load_i64(const long* p) {
    return __builtin_nontemporal_load(p);
}

// --- pass 1: partition edges by dst-bucket (int2 {src|dl<<20, w}) and
//     src local-ids by src-bucket (uchar) for the out-degree histogram. ---
__global__ void partition_kernel(const int* __restrict__ src, const int* __restrict__ dst,
                                 const float* __restrict__ ew,
                                 int* __restrict__ g_cur_d, int* __restrict__ g_cur_s,
                                 int2* __restrict__ pack_part, unsigned char* __restrict__ src_part,
                                 int m) {
    __shared__ int hist_d[NB], hist_s[NB];
    __shared__ int cur_d[NB], cur_s[NB];
    int t = threadIdx.x;
    for (int i = t; i < NB; i += 256) { hist_d[i] = 0; hist_s[i] = 0; }
    __syncthreads();
    int base_e = blockIdx.x * EPB;
    int es[16]; int ed[16]; float ewv[16];
#pragma unroll
    for (int k = 0; k < 16; k++) {
        int e = base_e + k * 256 + t;
        if (e < m) { es[k] = src[e]; ed[k] = dst[e]; ewv[k] = ew[e]; }
        else ed[k] = -1;
    }
#pragma unroll
    for (int k = 0; k < 16; k++) {
        if (ed[k] >= 0) {
            atomicAdd(&hist_d[ed[k] >> 8], 1);
            atomicAdd(&hist_s[es[k] >> 8], 1);
        }
    }
    __syncthreads();
    for (int i = t; i < NB; i += 256) {
        int c = hist_d[i];
        cur_d[i] = i * CAPB + (c ? atomicAdd(&g_cur_d[i], c) : 0);
        c = hist_s[i];
        cur_s[i] = i * CAPB + (c ? atomicAdd(&g_cur_s[i], c) : 0);
    }
    __syncthreads();
#pragma unroll
    for (int k = 0; k < 16; k++) {
        if (ed[k] >= 0) {
            int d = ed[k];
            int pos = atomicAdd(&cur_d[d >> 8], 1);
            pack_part[pos] = make_int2(es[k] | ((d & 255) << 20), __float_as_int(ewv[k]));
            int ps = atomicAdd(&cur_s[es[k] >> 8], 1);
            src_part[ps] = (unsigned char)(es[k] & 255);
        }
    }
}

// --- per src-bucket: out-degree in LDS -> norm_src ---
__global__ void srcnorm_kernel(const unsigned char* __restrict__ src_part,
                               const int* __restrict__ g_cur_s,
                               float* __restrict__ norm_src, int n) {
    __shared__ int cnt[256];
    int t = threadIdx.x, b = blockIdx.x;
    cnt[t] = 0;
    __syncthreads();
    int count = g_cur_s[b]; if (count > CAPB) count = CAPB;
    const unsigned char* p = src_part + (size_t)b * CAPB;
    for (int e = t; e < count; e += 256) atomicAdd(&cnt[p[e]], 1);
    __syncthreads();
    int node = b * 256 + t;
    if (node < n) {
        int c = cnt[t];
        norm_src[node] = rsqrtf((float)(c > 1 ? c : 1));
    }
}

// --- h1[n,32] (fp16) = (feat * norm_src) @ W1 ---
__global__ void transform1_kernel(const float* __restrict__ feat,
                                  const float* __restrict__ norm_src,
                                  const float* __restrict__ W1,
                                  __half* __restrict__ h1, int n) {
    __shared__ float sW[32 * 32];
    __shared__ float sF[8][32];
    int t = threadIdx.x;
    for (int i = t; i < 32 * 32; i += 256) sW[i] = W1[i];
    int node0 = blockIdx.x * 8;
    int local = t >> 5, col = t & 31;
    int node = node0 + local;
    float f = 0.0f;
    if (node < n) f = feat[node * 32 + col] * norm_src[node];
    sF[local][col] = f;
    __syncthreads();
    if (node < n) {
        float acc = 0.0f;
#pragma unroll
        for (int k = 0; k < 32; k++) acc += sF[local][k] * sW[k * 32 + col];
        h1[(size_t)node * 32 + col] = __float2half(acc);
    }
}

// --- layer-1: per-bucket LDS aggregation + fused norms/relu/W2 -> h2, norm_dst.
//     1024 threads: 64 edge slots x 16 half2-dims, 4-deep unroll. ---
__global__ __launch_bounds__(1024) void agg1_kernel(
        const __half* __restrict__ h1, const int2* __restrict__ pack_part,
        const int* __restrict__ g_cur_d, const float* __restrict__ norm_src,
        const float* __restrict__ W2, const float* __restrict__ b1,
        __half* __restrict__ h2, float* __restrict__ norm_dst, int n) {
    __shared__ float agg[256 * 33];   // 33.8 KB, stride 33
    __shared__ int cnt[256];
    __shared__ float sW2[512];
    __shared__ float sB1[32];
    int t = threadIdx.x, b = blockIdx.x;
    for (int i = t; i < 256 * 33; i += 1024) agg[i] = 0.0f;
    if (t < 256) cnt[t] = 0;
    if (t >= 256 && t < 768) sW2[t - 256] = W2[t - 256];
    if (t >= 768 && t < 800) sB1[t - 768] = b1[t - 768];
    __syncthreads();
    int count = g_cur_d[b]; if (count > CAPB) count = CAPB;
    const long* pk = (const long*)(pack_part + (size_t)b * CAPB);
    const __half2* tv = (const __half2*)h1;   // 16 half2 per row
    int dh = t & 15;     // half2 dim index
    int el = t >> 4;     // edge slot 0..63
    int j = el;
    for (; j + 192 < count; j += 256) {
        long q0 = nt_load_i64(pk + j);
        long q1 = nt_load_i64(pk + j + 64);
        long q2 = nt_load_i64(pk + j + 128);
        long q3 = nt_load_i64(pk + j + 192);
        int x0 = (int)q0, x1 = (int)q1, x2 = (int)q2, x3 = (int)q3;
        float2 v0 = __half22float2(tv[(size_t)(x0 & 0xFFFFF) * 16 + dh]);
        float2 v1 = __half22float2(tv[(size_t)(x1 & 0xFFFFF) * 16 + dh]);
        float2 v2 = __half22float2(tv[(size_t)(x2 & 0xFFFFF) * 16 + dh]);
        float2 v3 = __half22float2(tv[(size_t)(x3 & 0xFFFFF) * 16 + dh]);
        float w0 = __int_as_float((int)(q0 >> 32)), w1 = __int_as_float((int)(q1 >> 32));
        float w2 = __int_as_float((int)(q2 >> 32)), w3 = __int_as_float((int)(q3 >> 32));
        int d0 = (x0 >> 20) & 0xFF, d1 = (x1 >> 20) & 0xFF;
        int d2 = (x2 >> 20) & 0xFF, d3 = (x3 >> 20) & 0xFF;
        atomicAdd(&agg[d0 * 33 + 2 * dh],     v0.x * w0);
        atomicAdd(&agg[d0 * 33 + 2 * dh + 1], v0.y * w0);
        atomicAdd(&agg[d1 * 33 + 2 * dh],     v1.x * w1);
        atomicAdd(&agg[d1 * 33 + 2 * dh + 1], v1.y * w1);
        atomicAdd(&agg[d2 * 33 + 2 * dh],     v2.x * w2);
        atomicAdd(&agg[d2 * 33 + 2 * dh + 1], v2.y * w2);
        atomicAdd(&agg[d3 * 33 + 2 * dh],     v3.x * w3);
        atomicAdd(&agg[d3 * 33 + 2 * dh + 1], v3.y * w3);
        if (dh == 0) {
            atomicAdd(&cnt[d0], 1); atomicAdd(&cnt[d1], 1);
            atomicAdd(&cnt[d2], 1); atomicAdd(&cnt[d3], 1);
        }
    }
    for (; j < count; j += 64) {
        long q = nt_load_i64(pk + j);
        int x = (int)q;
        float2 v = __half22float2(tv[(size_t)(x & 0xFFFFF) * 16 + dh]);
        float w = __int_as_float((int)(q >> 32));
        int dl = (x >> 20) & 0xFF;
        atomicAdd(&agg[dl * 33 + 2 * dh],     v.x * w);
        atomicAdd(&agg[dl * 33 + 2 * dh + 1], v.y * w);
        if (dh == 0) atomicAdd(&cnt[dl], 1);
    }
    __syncthreads();
    int node0 = b << 8;
    // x = relu(agg*nd + b1) * ns, in place; write norm_dst
    for (int o = t; o < 256 * 32; o += 1024) {
        int i = o >> 5, k = o & 31;
        int node = node0 + i;
        if (node < n) {
            int c = cnt[i];
            float nd = rsqrtf((float)(c > 1 ? c : 1));
            float ns = norm_src[node];
            float x = agg[i * 33 + k] * nd + sB1[k];
            agg[i * 33 + k] = fmaxf(x, 0.0f) * ns;
        }
    }
    if (t < 256) {
        int node = node0 + t;
        if (node < n) {
            int c = cnt[t];
            norm_dst[node] = rsqrtf((float)(c > 1 ? c : 1));
        }
    }
    __syncthreads();
    // h2[256,16] = x[256,32] @ W2[32,16]
    for (int o = t; o < 256 * 16; o += 1024) {
        int i = o >> 4, cc = o & 15;
        int node = node0 + i;
        if (node < n) {
            float acc = 0.0f;
#pragma unroll
            for (int k = 0; k < 32; k++) acc += agg[i * 33 + k] * sW2[k * 16 + cc];
            h2[(size_t)node * 16 + cc] = __float2half(acc);
        }
    }
}

// --- layer-2: per-bucket LDS aggregation + fused norm/bias -> out.
//     1024 threads: 128 edge slots x 8 half2-dims, 4-deep unroll. ---
__global__ __launch_bounds__(1024) void agg2_kernel(
        const __half* __restrict__ h2, const int2* __restrict__ pack_part,
        const int* __restrict__ g_cur_d, const float* __restrict__ norm_dst,
        const float* __restrict__ b2, float* __restrict__ out, int n) {
    __shared__ float agg[256 * 17];   // 17.4 KB
    __shared__ float sB2[16];
    int t = threadIdx.x, b = blockIdx.x;
    for (int i = t; i < 256 * 17; i += 1024) agg[i] = 0.0f;
    if (t < 16) sB2[t] = b2[t];
    __syncthreads();
    int count = g_cur_d[b]; if (count > CAPB) count = CAPB;
    const long* pk = (const long*)(pack_part + (size_t)b * CAPB);
    const __half2* tv = (const __half2*)h2;   // 8 half2 per row
    int dh = t & 7;      // half2 dim index
    int el = t >> 3;     // edge slot 0..127
    int j = el;
    for (; j + 384 < count; j += 512) {
        long q0 = nt_load_i64(pk + j);
        long q1 = nt_load_i64(pk + j + 128);
        long q2 = nt_load_i64(pk + j + 256);
        long q3 = nt_load_i64(pk + j + 384);
        int x0 = (int)q0, x1 = (int)q1, x2 = (int)q2, x3 = (int)q3;
        float2 v0 = __half22float2(tv[(size_t)(x0 & 0xFFFFF) * 8 + dh]);
        float2 v1 = __half22float2(tv[(size_t)(x1 & 0xFFFFF) * 8 + dh]);
        float2 v2 = __half22float2(tv[(size_t)(x2 & 0xFFFFF) * 8 + dh]);
        float2 v3 = __half22float2(tv[(size_t)(x3 & 0xFFFFF) * 8 + dh]);
        float w0 = __int_as_float((int)(q0 >> 32)), w1 = __int_as_float((int)(q1 >> 32));
        float w2 = __int_as_float((int)(q2 >> 32)), w3 = __int_as_float((int)(q3 >> 32));
        int d0 = (x0 >> 20) & 0xFF, d1 = (x1 >> 20) & 0xFF;
        int d2 = (x2 >> 20) & 0xFF, d3 = (x3 >> 20) & 0xFF;
        atomicAdd(&agg[d0 * 17 + 2 * dh],     v0.x * w0);
        atomicAdd(&agg[d0 * 17 + 2 * dh + 1], v0.y * w0);
        atomicAdd(&agg[d1 * 17 + 2 * dh],     v1.x * w1);
        atomicAdd(&agg[d1 * 17 + 2 * dh + 1], v1.y * w1);
        atomicAdd(&agg[d2 * 17 + 2 * dh],     v2.x * w2);
        atomicAdd(&agg[d2 * 17 + 2 * dh + 1], v2.y * w2);
        atomicAdd(&agg[d3 * 17 + 2 * dh],     v3.x * w3);
        atomicAdd(&agg[d3 * 17 + 2 * dh + 1], v3.y * w3);
    }
    for (; j < count; j += 128) {
        long q = nt_load_i64(pk + j);
        int x = (int)q;
        float2 v = __half22float2(tv[(size_t)(x & 0xFFFFF) * 8 + dh]);
        float w = __int_as_float((int)(q >> 32));
        int dl = (x >> 20) & 0xFF;
        atomicAdd(&agg[dl * 17 + 2 * dh],     v.x * w);
        atomicAdd(&agg[dl * 17 + 2 * dh + 1], v.y * w);
    }
    __syncthreads();
    int node0 = b << 8;
    for (int o = t; o < 256 * 8; o += 1024) {
        int i = o >> 3, ch = o & 7;
        int node = node0 + i;
        if (node < n) {
            float nd = norm_dst[node];
            float2 v;
            v.x = agg[i * 17 + 2 * ch]     * nd + sB2[2 * ch];
            v.y = agg[i * 17 + 2 * ch + 1] * nd + sB2[2 * ch + 1];
            ((float2*)out)[(size_t)node * 8 + ch] = v;
        }
    }
}

extern "C" void kernel_launch(void* const* d_in, const int* in_sizes, int n_in,
                              void* d_out, int out_size, void* d_ws, size_t ws_size,
                              hipStream_t stream) {
    const float* feat = (const float*)d_in[0];
    const int*   src  = (const int*)d_in[1];
    const int*   dst  = (const int*)d_in[2];
    const float* ew   = (const float*)d_in[3];
    const float* W1   = (const float*)d_in[4];
    const float* b1   = (const float*)d_in[5];
    const float* W2   = (const float*)d_in[6];
    const float* b2   = (const float*)d_in[7];
    float* out = (float*)d_out;

    const int n = in_sizes[0] / 32;  // 100000
    const int m = in_sizes[1];       // 1600000

    // ws: pack_part[NB*CAPB int2] | h1 half[32n] | h2 half[16n] |
    //     norm_src[n] | norm_dst[n] | g_cur_d[NB] | g_cur_s[NB] | src_part uchar[NB*CAPB]
    char* wsb = (char*)d_ws;
    int2*   pack_part = (int2*)wsb;
    __half* h1        = (__half*)(pack_part + (size_t)NB * CAPB);
    __half* h2        = h1 + 32 * (size_t)n;
    float*  norm_src  = (float*)(h2 + 16 * (size_t)n);
    float*  norm_dst  = norm_src + n;
    int*    g_cur_d   = (int*)(norm_dst + n);
    int*    g_cur_s   = g_cur_d + NB;
    unsigned char* src_part = (unsigned char*)(g_cur_s + NB);

    hipMemsetAsync(g_cur_d, 0, 2 * NB * sizeof(int), stream);

    partition_kernel<<<(m + EPB - 1) / EPB, 256, 0, stream>>>(src, dst, ew, g_cur_d, g_cur_s,
                                                              pack_part, src_part, m);
    srcnorm_kernel<<<NB, 256, 0, stream>>>(src_part, g_cur_s, norm_src, n);
    transform1_kernel<<<(n + 7) / 8, 256, 0, stream>>>(feat, norm_src, W1, h1, n);
    agg1_kernel<<<NB, 1024, 0, stream>>>(h1, pack_part, g_cur_d, norm_src, W2, b1,
                                         h2, norm_dst, n);
    agg2_kernel<<<NB, 1024, 0, stream>>>(h2, pack_part, g_cur_d, norm_dst, b2, out, n);
}

// Round 11
// 208.854 us; speedup vs baseline: 3.2071x; 3.2071x over previous
//
#include <hip/hip_runtime.h>
#include <hip/hip_fp16.h>

// GCN 2-layer. R9 structure (the 213us champion): partition -> merged CSR+norms
// -> transform1 -> gather1 (4 nodes/wave) -> gather2 (8 nodes/wave).
// R11 change: partition stages edges in LDS grouped by bucket, so global
// writes stream out in coalesced per-bucket runs instead of 64-way scatter.

#define NB   391      // buckets = ceil(100000/256); bucket = id >> 8
#define CAPB 5504     // padded per-bucket edge capacity (avg 4092, +22 sigma)
#define EPB  4096     // edges per partition block (16/thread)

__device__ __forceinline__ long nt_load_i64(const long* p) {
    return __builtin_nontemporal_load(p);
}

// --- pass 1: partition edges by dst-bucket; LDS-staged, coalesced run writes ---
__global__ __launch_bounds__(256) void partition_kernel(
        const int* __restrict__ src, const int* __restrict__ dst,
        const float* __restrict__ ew,
        int* __restrict__ g_cur_d, int* __restrict__ g_cur_s,
        int2* __restrict__ pack_part, unsigned char* __restrict__ src_part, int m) {
    __shared__ int hist_d[NB], hist_s[NB];
    __shared__ int lbase_d[NB], lbase_s[NB];
    __shared__ int gbase_d[NB], gbase_s[NB];
    __shared__ int cur_d[NB], cur_s[NB];
    __shared__ int sc[2][512];
    __shared__ long stage[EPB];            // 32 KB
    __shared__ unsigned short dbuck[EPB];  // 8 KB
    __shared__ unsigned char  sstage[EPB]; // 4 KB
    __shared__ unsigned short sbuck[EPB];  // 8 KB
    int t = threadIdx.x;
    for (int i = t; i < NB; i += 256) {
        hist_d[i] = 0; hist_s[i] = 0; cur_d[i] = 0; cur_s[i] = 0;
    }
    __syncthreads();
    int base_e = blockIdx.x * EPB;
    int total = m - base_e; if (total > EPB) total = EPB;
    int es[16], ed[16]; float wv[16];
#pragma unroll
    for (int k = 0; k < 16; k++) {
        int e = base_e + k * 256 + t;
        if (e < m) { es[k] = src[e]; ed[k] = dst[e]; wv[k] = ew[e]; }
        else ed[k] = -1;
    }
#pragma unroll
    for (int k = 0; k < 16; k++) {
        if (ed[k] >= 0) {
            atomicAdd(&hist_d[ed[k] >> 8], 1);
            atomicAdd(&hist_s[es[k] >> 8], 1);
        }
    }
    __syncthreads();
    // exclusive scan of hist_d over 512 slots (ping-pong)
    for (int i = t; i < 512; i += 256) sc[0][i] = (i < NB) ? hist_d[i] : 0;
    __syncthreads();
    int pp = 0;
    for (int off = 1; off < 512; off <<= 1) {
        for (int i = t; i < 512; i += 256)
            sc[1 - pp][i] = sc[pp][i] + (i >= off ? sc[pp][i - off] : 0);
        __syncthreads();
        pp ^= 1;
    }
    for (int i = t; i < NB; i += 256) lbase_d[i] = sc[pp][i] - hist_d[i];
    __syncthreads();
    // exclusive scan of hist_s
    for (int i = t; i < 512; i += 256) sc[0][i] = (i < NB) ? hist_s[i] : 0;
    __syncthreads();
    pp = 0;
    for (int off = 1; off < 512; off <<= 1) {
        for (int i = t; i < 512; i += 256)
            sc[1 - pp][i] = sc[pp][i] + (i >= off ? sc[pp][i - off] : 0);
        __syncthreads();
        pp ^= 1;
    }
    for (int i = t; i < NB; i += 256) lbase_s[i] = sc[pp][i] - hist_s[i];
    __syncthreads();
    // reserve global space per bucket
    for (int i = t; i < NB; i += 256) {
        int c = hist_d[i];
        gbase_d[i] = i * CAPB + (c ? atomicAdd(&g_cur_d[i], c) : 0);
        c = hist_s[i];
        gbase_s[i] = i * CAPB + (c ? atomicAdd(&g_cur_s[i], c) : 0);
    }
    __syncthreads();
    // scatter into LDS stage, grouped by bucket
#pragma unroll
    for (int k = 0; k < 16; k++) {
        if (ed[k] >= 0) {
            int d = ed[k], s = es[k];
            int bd = d >> 8;
            int r = atomicAdd(&cur_d[bd], 1);
            int pos = lbase_d[bd] + r;
            stage[pos] = (long)(unsigned int)(s | ((d & 255) << 20)) |
                         ((long)__float_as_int(wv[k]) << 32);
            dbuck[pos] = (unsigned short)bd;
            int bs = s >> 8;
            int rs = atomicAdd(&cur_s[bs], 1);
            int ps = lbase_s[bs] + rs;
            sstage[ps] = (unsigned char)(s & 255);
            sbuck[ps] = (unsigned short)bs;
        }
    }
    __syncthreads();
    // stream out: consecutive slots in a bucket -> consecutive global addrs
    long* packl = (long*)pack_part;
    for (int i = t; i < total; i += 256) {
        int b = dbuck[i];
        packl[(size_t)gbase_d[b] + (i - lbase_d[b])] = stage[i];
    }
    for (int i = t; i < total; i += 256) {
        int b = sbuck[i];
        src_part[(size_t)gbase_s[b] + (i - lbase_s[b])] = sstage[i];
    }
}

// --- per bucket (512 threads): dst CSR (hist+scan+scatter in LDS) + both norms ---
__global__ void csr_kernel(const int2* __restrict__ pack_part,
                           const unsigned char* __restrict__ src_part,
                           const int* __restrict__ g_cur_d, const int* __restrict__ g_cur_s,
                           int2* __restrict__ csr, int2* __restrict__ rs_cnt,
                           float* __restrict__ norm_src, float* __restrict__ norm_dst, int n) {
    __shared__ int cnt[256];
    __shared__ int rowx[256];
    __shared__ int cur[256];
    __shared__ int cnt_s[256];
    extern __shared__ int2 stage[];  // CAPB entries (44 KB)
    int t = threadIdx.x, b = blockIdx.x;
    if (t < 256) { cnt[t] = 0; cur[t] = 0; cnt_s[t] = 0; }
    __syncthreads();
    int count = g_cur_d[b]; if (count > CAPB) count = CAPB;
    int count_s = g_cur_s[b]; if (count_s > CAPB) count_s = CAPB;
    const int2* p = pack_part + (size_t)b * CAPB;
    const unsigned char* sp = src_part + (size_t)b * CAPB;
    for (int e = t; e < count; e += 512) atomicAdd(&cnt[p[e].x >> 20], 1);
    for (int e = t; e < count_s; e += 512) atomicAdd(&cnt_s[sp[e]], 1);
    __syncthreads();
    if (t < 256) {
        int node = b * 256 + t;
        if (node < n) {
            int cs = cnt_s[t];
            norm_src[node] = rsqrtf((float)(cs > 1 ? cs : 1));
        }
    }
    int c0 = 0;
    if (t < 256) { c0 = cnt[t]; rowx[t] = c0; }
    __syncthreads();
    for (int off = 1; off < 256; off <<= 1) {
        int v = 0;
        if (t < 256 && t >= off) v = rowx[t - off];
        __syncthreads();
        if (t < 256) rowx[t] += v;
        __syncthreads();
    }
    if (t < 256) {
        int excl = rowx[t] - c0;
        rowx[t] = excl;
        int node = b * 256 + t;
        if (node < n) {
            rs_cnt[node] = make_int2(b * CAPB + excl, c0);
            norm_dst[node] = rsqrtf((float)(c0 > 1 ? c0 : 1));
        }
    }
    __syncthreads();
    for (int e = t; e < count; e += 512) {
        int2 v = p[e];
        int dl = v.x >> 20;
        int r = atomicAdd(&cur[dl], 1);
        stage[rowx[dl] + r] = make_int2(v.x & 0x1FFFF, v.y);
    }
    __syncthreads();
    int2* outp = csr + (size_t)b * CAPB;
    for (int e = t; e < count; e += 512) outp[e] = stage[e];
}

// --- h1[n,32] (fp16) = (feat * norm_src) @ W1 ---
__global__ void transform1_kernel(const float* __restrict__ feat,
                                  const float* __restrict__ norm_src,
                                  const float* __restrict__ W1,
                                  __half* __restrict__ h1, int n) {
    __shared__ float sW[32 * 32];
    __shared__ float sF[8][32];
    int t = threadIdx.x;
    for (int i = t; i < 32 * 32; i += 256) sW[i] = W1[i];
    int node0 = blockIdx.x * 8;
    int local = t >> 5, col = t & 31;
    int node = node0 + local;
    float f = 0.0f;
    if (node < n) f = feat[node * 32 + col] * norm_src[node];
    sF[local][col] = f;
    __syncthreads();
    if (node < n) {
        float acc = 0.0f;
#pragma unroll
        for (int k = 0; k < 32; k++) acc += sF[local][k] * sW[k * 32 + col];
        h1[(size_t)node * 32 + col] = __float2half(acc);
    }
}

// --- gather1 + fused transform2: 4 nodes per wave (16 lanes each, lane owns
//     2 dims of 32) -> no cross-lane reduction; 4-deep unroll per node. ---
__global__ void gather1_fused_kernel(const __half* __restrict__ h1, const int2* __restrict__ csr,
                                     const int2* __restrict__ rs_cnt,
                                     const float* __restrict__ norm_src, const float* __restrict__ norm_dst,
                                     const float* __restrict__ W2, const float* __restrict__ b1,
                                     __half* __restrict__ h2, int n) {
    __shared__ float sW2[32 * 16];
    __shared__ float sX[4][4][32];
    int t = threadIdx.x;
    for (int i = t; i < 512; i += 256) sW2[i] = W2[i];
    __syncthreads();
    int w = t >> 6, lane = t & 63;
    int q = lane >> 4;      // sub-node within wave
    int dh = lane & 15;     // half2 index (dims 2dh, 2dh+1)
    int node = (blockIdx.x * 4 + w) * 4 + q;
    bool valid = node < n;
    int2 rc = valid ? rs_cnt[node] : make_int2(0, 0);
    long base = rc.x;
    int c = rc.y;
    const __half2* tv = (const __half2*)h1;   // 16 half2 per row
    const long* csrl = (const long*)csr;
    float ax0 = 0.f, ay0 = 0.f, ax1 = 0.f, ay1 = 0.f;
    float ax2 = 0.f, ay2 = 0.f, ax3 = 0.f, ay3 = 0.f;
    int j = 0;
    for (; j + 3 < c; j += 4) {
        long q0 = nt_load_i64(csrl + base + j);
        long q1 = nt_load_i64(csrl + base + j + 1);
        long q2 = nt_load_i64(csrl + base + j + 2);
        long q3 = nt_load_i64(csrl + base + j + 3);
        float2 v0 = __half22float2(tv[(size_t)(int)q0 * 16 + dh]);
        float2 v1 = __half22float2(tv[(size_t)(int)q1 * 16 + dh]);
        float2 v2 = __half22float2(tv[(size_t)(int)q2 * 16 + dh]);
        float2 v3 = __half22float2(tv[(size_t)(int)q3 * 16 + dh]);
        float w0 = __int_as_float((int)(q0 >> 32)), w1 = __int_as_float((int)(q1 >> 32));
        float w2 = __int_as_float((int)(q2 >> 32)), w3 = __int_as_float((int)(q3 >> 32));
        ax0 += v0.x * w0; ay0 += v0.y * w0;
        ax1 += v1.x * w1; ay1 += v1.y * w1;
        ax2 += v2.x * w2; ay2 += v2.y * w2;
        ax3 += v3.x * w3; ay3 += v3.y * w3;
    }
    for (; j < c; j++) {
        long qq = nt_load_i64(csrl + base + j);
        float2 v = __half22float2(tv[(size_t)(int)qq * 16 + dh]);
        float ww = __int_as_float((int)(qq >> 32));
        ax0 += v.x * ww; ay0 += v.y * ww;
    }
    float ax = (ax0 + ax1) + (ax2 + ax3);
    float ay = (ay0 + ay1) + (ay2 + ay3);
    if (valid) {
        float nd = norm_dst[node], ns = norm_src[node];
        sX[w][q][2 * dh]     = fmaxf(ax * nd + b1[2 * dh],     0.0f) * ns;
        sX[w][q][2 * dh + 1] = fmaxf(ay * nd + b1[2 * dh + 1], 0.0f) * ns;
    }
    // wave-synchronous LDS use (same wave wrote sX[w][q])
    if (valid) {
        float o = 0.0f;
#pragma unroll
        for (int k = 0; k < 32; k++) o += sX[w][q][k] * sW2[k * 16 + dh];
        h2[(size_t)node * 16 + dh] = __float2half(o);
    }
}

// --- gather2 + fused epilogue: 8 nodes per wave (8 lanes each, lane owns
//     2 dims of 16) -> fully lane-local, no LDS. ---
__global__ void gather2_kernel(const __half* __restrict__ h2, const int2* __restrict__ csr,
                               const int2* __restrict__ rs_cnt,
                               const float* __restrict__ norm_dst, const float* __restrict__ b2,
                               float* __restrict__ out, int n) {
    int t = threadIdx.x;
    int w = t >> 6, lane = t & 63;
    int q = lane >> 3;     // sub-node within wave (0..7)
    int dh = lane & 7;     // half2 index (dims 2dh, 2dh+1)
    int node = (blockIdx.x * 4 + w) * 8 + q;
    bool valid = node < n;
    int2 rc = valid ? rs_cnt[node] : make_int2(0, 0);
    long base = rc.x;
    int c = rc.y;
    const __half2* tv = (const __half2*)h2;   // 8 half2 per row
    const long* csrl = (const long*)csr;
    float ax0 = 0.f, ay0 = 0.f, ax1 = 0.f, ay1 = 0.f;
    float ax2 = 0.f, ay2 = 0.f, ax3 = 0.f, ay3 = 0.f;
    int j = 0;
    for (; j + 3 < c; j += 4) {
        long q0 = nt_load_i64(csrl + base + j);
        long q1 = nt_load_i64(csrl + base + j + 1);
        long q2 = nt_load_i64(csrl + base + j + 2);
        long q3 = nt_load_i64(csrl + base + j + 3);
        float2 v0 = __half22float2(tv[(size_t)(int)q0 * 8 + dh]);
        float2 v1 = __half22float2(tv[(size_t)(int)q1 * 8 + dh]);
        float2 v2 = __half22float2(tv[(size_t)(int)q2 * 8 + dh]);
        float2 v3 = __half22float2(tv[(size_t)(int)q3 * 8 + dh]);
        float w0 = __int_as_float((int)(q0 >> 32)), w1 = __int_as_float((int)(q1 >> 32));
        float w2 = __int_as_float((int)(q2 >> 32)), w3 = __int_as_float((int)(q3 >> 32));
        ax0 += v0.x * w0; ay0 += v0.y * w0;
        ax1 += v1.x * w1; ay1 += v1.y * w1;
        ax2 += v2.x * w2; ay2 += v2.y * w2;
        ax3 += v3.x * w3; ay3 += v3.y * w3;
    }
    for (; j < c; j++) {
        long qq = nt_load_i64(csrl + base + j);
        float2 v = __half22float2(tv[(size_t)(int)qq * 8 + dh]);
        float ww = __int_as_float((int)(qq >> 32));
        ax0 += v.x * ww; ay0 += v.y * ww;
    }
    float ax = (ax0 + ax1) + (ax2 + ax3);
    float ay = (ay0 + ay1) + (ay2 + ay3);
    if (valid) {
        float nd = norm_dst[node];
        float2 o;
        o.x = ax * nd + b2[2 * dh];
        o.y = ay * nd + b2[2 * dh + 1];
        ((float2*)out)[(size_t)node * 8 + dh] = o;
    }
}

extern "C" void kernel_launch(void* const* d_in, const int* in_sizes, int n_in,
                              void* d_out, int out_size, void* d_ws, size_t ws_size,
                              hipStream_t stream) {
    const float* feat = (const float*)d_in[0];
    const int*   src  = (const int*)d_in[1];
    const int*   dst  = (const int*)d_in[2];
    const float* ew   = (const float*)d_in[3];
    const float* W1   = (const float*)d_in[4];
    const float* b1   = (const float*)d_in[5];
    const float* W2   = (const float*)d_in[6];
    const float* b2   = (const float*)d_in[7];
    float* out = (float*)d_out;

    const int n = in_sizes[0] / 32;  // 100000
    const int m = in_sizes[1];       // 1600000

    // ws: pack_part[NB*CAPB int2] | csr[NB*CAPB int2] | h1 half[32n] | h2 half[16n] |
    //     norm_src[n] | norm_dst[n] | rs_cnt int2[n] | g_cur_d[NB] | g_cur_s[NB] |
    //     src_part uchar[NB*CAPB]
    char* wsb = (char*)d_ws;
    int2*   pack_part = (int2*)wsb;
    int2*   csr       = pack_part + (size_t)NB * CAPB;
    __half* h1        = (__half*)(csr + (size_t)NB * CAPB);
    __half* h2        = h1 + 32 * (size_t)n;
    float*  norm_src  = (float*)(h2 + 16 * (size_t)n);
    float*  norm_dst  = norm_src + n;
    int2*   rs_cnt    = (int2*)(norm_dst + n);
    int*    g_cur_d   = (int*)(rs_cnt + n);
    int*    g_cur_s   = g_cur_d + NB;
    unsigned char* src_part = (unsigned char*)(g_cur_s + NB);

    hipMemsetAsync(g_cur_d, 0, 2 * NB * sizeof(int), stream);

    partition_kernel<<<(m + EPB - 1) / EPB, 256, 0, stream>>>(src, dst, ew, g_cur_d, g_cur_s,
                                                              pack_part, src_part, m);
    csr_kernel<<<NB, 512, CAPB * sizeof(int2), stream>>>(pack_part, src_part, g_cur_d, g_cur_s,
                                                         csr, rs_cnt, norm_src, norm_dst, n);
    transform1_kernel<<<(n + 7) / 8, 256, 0, stream>>>(feat, norm_src, W1, h1, n);
    gather1_fused_kernel<<<(n + 15) / 16, 256, 0, stream>>>(h1, csr, rs_cnt,
                                                            norm_src, norm_dst, W2, b1, h2, n);
    gather2_kernel<<<(n + 31) / 32, 256, 0, stream>>>(h2, csr, rs_cnt, norm_dst, b2, out, n);
}